// Round 1
// baseline (118.383 us; speedup 1.0000x reference)
//
#include <hip/hip_runtime.h>
#include <math.h>

#define IMG 416
#define N_ANG 320
#define N_DET 416
#define N_SAMP 416

// ---------------------------------------------------------------------------
// Corner-packed fp8 image Q: entry (r,c) is a 32-bit word holding fp8 of the
// diff image at {(r,c),(r+1,c),(r,c+1),(r+1,c+1)} (bytes 0,1,2,3). One
// ds_read_b32 + two v_cvt_pk_f32_fp8 yields the whole bilinear footprint.
// Entry (r,c) lives at Q[(r+4)*424 + (c+4)], valid for r,c in [-4, 423],
// zero outside the 416x416 image.
// ---------------------------------------------------------------------------
#define QSTRIDE 424
#define QROWS   428
#define QWORDS  (QROWS * QSTRIDE)                 // 181472
#define QALLOC_BYTES ((size_t)(QWORDS + 32) * 4)  // + tail pad for x4 staging

#define SPLANE  (N_ANG * N_DET)                   // 133120 rays
#define SBYTES1 ((size_t)SPLANE * sizeof(float))
#define WS_ATM  (QALLOC_BYTES + SBYTES1)          // ~1.26 MB

// 4x4 tiles of 105x105 entries per angle; staged with 2-entry margins.
#define TILE  105
#define LROWS 108
#define LSTR  116                                  // words per LDS row
#define NCH   29                                   // uint4 chunks per row
#define LDSW  (LROWS * LSTR)                       // 12528 words = 50112 B

typedef float vfloat2 __attribute__((ext_vector_type(2)));

// ---------------------------------------------------------------------------
// Kernel A: build corner-packed fp8 diff image Q; zero S plane and out.
// ---------------------------------------------------------------------------
__global__ __launch_bounds__(256) void pack_q(const float* __restrict__ a,
                                              const float* __restrict__ b,
                                              unsigned int* __restrict__ Q,
                                              float* __restrict__ S,
                                              float* __restrict__ out) {
    int i = blockIdx.x * 256 + threadIdx.x;
    if (i == 0) out[0] = 0.0f;
    if (i < QWORDS) {
        int pr = i / QSTRIDE;
        int pc = i - pr * QSTRIDE;
        int r = pr - 4;
        int c = pc - 4;
        auto dv = [&](int rr, int cc) -> float {
            bool in = ((unsigned)rr < (unsigned)IMG) & ((unsigned)cc < (unsigned)IMG);
            int idx = in ? rr * IMG + cc : 0;
            float v = a[idx] - b[idx];
            return in ? v : 0.0f;
        };
        unsigned int u = __builtin_amdgcn_cvt_pk_fp8_f32(dv(r, c), dv(r + 1, c), 0u, false);
        u = __builtin_amdgcn_cvt_pk_fp8_f32(dv(r, c + 1), dv(r + 1, c + 1), u, true);
        Q[i] = u;
    } else {
        int j = i - QWORDS;
        if (j < SPLANE) S[j] = 0.0f;
    }
}

__global__ void zero_out_kernel(float* __restrict__ out) {
    if (threadIdx.x == 0) out[0] = 0.0f;
}

// ---------------------------------------------------------------------------
// Kernel B: block = (angle, 4x4 tile). Stage the tile (+2-entry margins) of
// corner-packed words into LDS, then thread d marches its ray's exact sample
// sub-range inside the tile box (half-open clip -> each sample owned by
// exactly one tile). Bilinear = 1x ds_read_b32 + 2 HW fp8 unpacks.
// Tile partials accumulate into S via atomicAdd.
// ---------------------------------------------------------------------------
__global__ __launch_bounds__(448) void proj_q(const unsigned int* __restrict__ Q,
                                              float* __restrict__ S,
                                              float theta_step, float gmax,
                                              float gstep, float t0,
                                              float dtstep) {
    __shared__ unsigned int L[LDSW];               // 50112 B -> 3 blocks/CU

    const int blk  = blockIdx.x;                   // 0..5119
    const int a    = blk >> 4;
    const int tile = blk & 15;
    const int ty   = tile >> 2, tx = tile & 3;

    const int rli = -2 + 105 * ty;                 // box rows [rli, rli+105)
    const int cli = -2 + 105 * tx;                 // box cols [cli, cli+105)

    // staged entry cols start at cli-2, aligned down to a x4 word boundary
    const int c4v  = cli + 2;                      // Q word col of (cli-2)
    const int c0w  = c4v & ~3;
    const int coff = c4v - c0w;                    // 0..3
    const int qrow0 = rli + 2;                     // Q row of entry row rli-2

    // --- cooperative stage: LROWS x NCH uint4 chunks (coalesced) -----------
    {
        const uint4* Q4 = (const uint4*)Q;
        const int gbase4 = qrow0 * (QSTRIDE / 4) + (c0w >> 2);
        for (int s = threadIdx.x; s < LROWS * NCH; s += 448) {
            int rr = s / NCH;
            int k  = s - rr * NCH;
            uint4 w = Q4[gbase4 + rr * (QSTRIDE / 4) + k];
            *(uint4*)(&L[rr * LSTR + 4 * k]) = w;
        }
    }
    __syncthreads();

    const int d = threadIdx.x;
    if (d >= N_DET) return;

    const float theta = (float)a * theta_step;
    const float gamma = fmaf((float)d, gstep, -gmax);
    float s1, c1, s2, c2;
    sincosf(theta, &s1, &c1);
    sincosf(theta + gamma, &s2, &c2);
    const float sx = fmaf(1075.0f, c1, 207.5f);
    const float sy = fmaf(1075.0f, s1, 207.5f);

    // col(k) = C0 - k*dc ; row(k) = R0 - k*dr   (k = 0..415)
    const float C0 = fmaf(-t0, c2, sx), dc = dtstep * c2;
    const float R0 = fmaf(-t0, s2, sy), dr = dtstep * s2;

    // tile box, half-open: col in [cl,ch), row in [rl,rh)
    const float cl = (float)cli, ch = (float)(cli + 105);
    const float rl = (float)rli, rh = (float)(rli + 105);

    int klo = 0, khi = N_SAMP - 1;
    auto clip1 = [&](float X0, float dX, float lo, float hi) {
        if (fabsf(dX) < 1e-8f) {
            if (!(X0 >= lo && X0 < hi)) { klo = 1; khi = 0; }
        } else {
            float x1 = (X0 - hi) / dX;        // strict side
            float x2 = (X0 - lo) / dX;        // inclusive side
            x1 = fminf(fmaxf(x1, -1e6f), 1e6f);
            x2 = fminf(fmaxf(x2, -1e6f), 1e6f);
            int lo_k, hi_k;
            if (dX > 0.0f) { lo_k = (int)floorf(x1) + 1; hi_k = (int)floorf(x2); }
            else           { lo_k = (int)ceilf(x2);      hi_k = (int)ceilf(x1) - 1; }
            klo = max(klo, lo_k);
            khi = min(khi, hi_k);
        }
    };
    clip1(C0, dc, cl, ch);
    clip1(R0, dr, rl, rh);

    if (klo <= khi) {
        // LDS-relative coords; margins guarantee >= 0 inside the box.
        const float cbias = (float)(cli - coff - 2);
        const float rbias = (float)(rli - 2);
        float colR = fmaf(-(float)klo, dc, C0) - cbias;
        float rowR = fmaf(-(float)klo, dr, R0) - rbias;
        float acc = 0.0f;
        #pragma unroll 4
        for (int k = klo; k <= khi; ++k) {
            const float cf = floorf(colR);
            const float rf = floorf(rowR);
            const float wc = colR - cf;
            const float wr = rowR - rf;
            const int widx = (int)fmaf(rf, (float)LSTR, cf);
            const unsigned int w = L[widx];
            const vfloat2 X = __builtin_amdgcn_cvt_pk_f32_fp8(w, false); // v00,v10
            const vfloat2 Y = __builtin_amdgcn_cvt_pk_f32_fp8(w, true);  // v01,v11
            const float top = fmaf(wc, Y[0] - X[0], X[0]);
            const float bot = fmaf(wc, Y[1] - X[1], X[1]);
            acc = fmaf(wr, bot - top, acc + top);
            colR -= dc;
            rowR -= dr;
        }
        atomicAdd(&S[a * N_DET + d], acc);
    }
}

// ---------------------------------------------------------------------------
// Kernel C: square each ray sum, reduce, scale.
// ---------------------------------------------------------------------------
__global__ __launch_bounds__(256) void reduce_q(const float* __restrict__ S,
                                                float* __restrict__ out,
                                                float coef) {
    const int i = blockIdx.x * 256 + threadIdx.x;
    float v = (i < SPLANE) ? S[i] : 0.0f;
    float sq = v * v;
    #pragma unroll
    for (int m = 32; m > 0; m >>= 1) sq += __shfl_down(sq, m, 64);
    __shared__ float w[4];
    const int lane = threadIdx.x & 63;
    if (lane == 0) w[threadIdx.x >> 6] = sq;
    __syncthreads();
    if (threadIdx.x == 0)
        atomicAdd(out, (w[0] + w[1] + w[2] + w[3]) * coef);
}

// ---------------------------------------------------------------------------
// Fallback (ws too small): fused one-thread-per-ray fp32 gather version.
// ---------------------------------------------------------------------------
__global__ __launch_bounds__(256) void proj_fused(const float* __restrict__ imgA,
                                                  const float* __restrict__ imgB,
                                                  float* __restrict__ out,
                                                  float theta_step, float gmax,
                                                  float gstep, float t0,
                                                  float dtstep, float coef) {
    const int idx = blockIdx.x * 256 + threadIdx.x;
    const int a  = idx / N_DET;
    const int dd = idx - a * N_DET;
    const float theta = (float)a * theta_step;
    const float gamma = fmaf((float)dd, gstep, -gmax);
    float s1, c1, s2, c2;
    sincosf(theta, &s1, &c1);
    sincosf(theta + gamma, &s2, &c2);
    const float sx = 1075.0f * c1 + 207.5f;
    const float sy = 1075.0f * s1 + 207.5f;
    float acc = 0.0f;
    #pragma unroll 4
    for (int s = 0; s < N_SAMP; ++s) {
        const float t   = fmaf((float)s, dtstep, t0);
        const float col = fmaf(-t, c2, sx);
        const float row = fmaf(-t, s2, sy);
        const float c0 = floorf(col);
        const float r0 = floorf(row);
        const float wc = col - c0;
        const float wr = row - r0;
        const int ci = (int)c0;
        const int ri = (int)r0;
        auto Gv = [&](int r, int c) -> float {
            if ((unsigned)r < (unsigned)IMG && (unsigned)c < (unsigned)IMG)
                return imgA[r * IMG + c] - imgB[r * IMG + c];
            return 0.0f;
        };
        const float v00 = Gv(ri, ci);
        const float v01 = Gv(ri, ci + 1);
        const float v10 = Gv(ri + 1, ci);
        const float v11 = Gv(ri + 1, ci + 1);
        const float top = fmaf(wc, v01 - v00, v00);
        const float bot = fmaf(wc, v11 - v10, v10);
        acc += fmaf(wr, bot - top, top);
    }
    float sq = acc * acc;
    #pragma unroll
    for (int o = 32; o > 0; o >>= 1) sq += __shfl_down(sq, o, 64);
    __shared__ float wsum[4];
    const int lane = threadIdx.x & 63;
    if (lane == 0) wsum[threadIdx.x >> 6] = sq;
    __syncthreads();
    if (threadIdx.x == 0)
        atomicAdd(out, (wsum[0] + wsum[1] + wsum[2] + wsum[3]) * coef);
}

extern "C" void kernel_launch(void* const* d_in, const int* in_sizes, int n_in,
                              void* d_out, int out_size, void* d_ws, size_t ws_size,
                              hipStream_t stream) {
    const float* in = (const float*)d_in[0];
    const float* tg = (const float*)d_in[1];
    float* out = (float*)d_out;

    const double half_diag = (IMG / 2.0) * sqrt(2.0);
    const double ray_len   = IMG * sqrt(2.0);
    const float  gmax      = (float)asin(half_diag / 1075.0);
    const float  gstep     = (float)(2.0 * (double)gmax / (N_DET - 1));
    const float  t0        = (float)(1075.0 - ray_len / 2.0);
    const float  dtstep    = (float)(ray_len / (N_SAMP - 1));
    const float  theta_step = (float)(2.0 * M_PI / N_ANG);
    const double dt        = ray_len / (N_SAMP - 1);
    const double SCALE     = 512.0 / 416.0 * 0.03;
    const float  coef      = (float)(dt * dt * SCALE / ((double)N_ANG * N_DET));

    if (ws_size >= WS_ATM) {
        unsigned int* Q = (unsigned int*)d_ws;
        float* S = (float*)((char*)d_ws + QALLOC_BYTES);
        const int packN = QWORDS + SPLANE;
        pack_q<<<(packN + 255) / 256, 256, 0, stream>>>(in, tg, Q, S, out);
        proj_q<<<N_ANG * 16, 448, 0, stream>>>(Q, S, theta_step, gmax, gstep,
                                               t0, dtstep);
        reduce_q<<<(SPLANE + 255) / 256, 256, 0, stream>>>(S, out, coef);
    } else {
        zero_out_kernel<<<1, 64, 0, stream>>>(out);
        proj_fused<<<(N_ANG * N_DET) / 256, 256, 0, stream>>>(
            in, tg, out, theta_step, gmax, gstep, t0, dtstep, coef);
    }
}

// Round 3
// 110.069 us; speedup vs baseline: 1.0755x; 1.0755x over previous
//
#include <hip/hip_runtime.h>
#include <math.h>

#define IMG 416
#define N_ANG 320
#define N_DET 416
#define N_SAMP 416

// ---------------------------------------------------------------------------
// Padded global fp8 image G: stride 464 B, 432 rows. Pixel (r,c) of the diff
// image lives at G[(r+8)*464 + (c+8)], zero outside [0,416)^2.
// ---------------------------------------------------------------------------
#define GSTRIDE 464
#define GROWS   432
#define GBYTES  ((size_t)GROWS * GSTRIDE)        // 200448
#define GWORDS  (GROWS * GSTRIDE / 4)            // 50112

#define SPLANE  (N_ANG * N_DET)                  // 133120 rays
#define SBYTES  ((size_t)4 * SPLANE * sizeof(float))
#define WSNEED  (GBYTES + SBYTES)

// LDS staged quadrant tile: up to 228 rows x 59 words (236 B). 59 is odd ->
// row-pair word stride hits all 32 banks. ALL 59 words of every staged row
// are written (from G, which is fully defined), so any 1-ULP edge slop in
// the ray march still reads deterministic data.
#define LROWS   228
#define LWPR    59                               // words per LDS row
#define LSTRIDE (LWPR * 4)                       // 236 B

typedef float vfloat2 __attribute__((ext_vector_type(2)));

// ---------------------------------------------------------------------------
// Kernel A: build padded fp8 diff image (word-granular, fully overwrites G);
// zero d_out.
// ---------------------------------------------------------------------------
__global__ __launch_bounds__(256) void pack_kernel(const float* __restrict__ a,
                                                   const float* __restrict__ b,
                                                   unsigned int* __restrict__ G,
                                                   float* __restrict__ out) {
    int i = blockIdx.x * 256 + threadIdx.x;
    if (i == 0) out[0] = 0.0f;
    if (i >= GWORDS) return;
    int pr = i / (GSTRIDE / 4);            // 116 words per padded row
    int wc = i - pr * (GSTRIDE / 4);
    int r  = pr - 8;
    int c0 = wc * 4 - 8;
    float v[4];
    #pragma unroll
    for (int j = 0; j < 4; ++j) {
        int c = c0 + j;
        float val = 0.0f;
        if ((unsigned)r < (unsigned)IMG && (unsigned)c < (unsigned)IMG) {
            int idx = r * IMG + c;
            val = a[idx] - b[idx];
        }
        v[j] = val;
    }
    unsigned int u = __builtin_amdgcn_cvt_pk_fp8_f32(v[0], v[1], 0u, false);
    u = __builtin_amdgcn_cvt_pk_fp8_f32(v[2], v[3], u, true);
    G[i] = u;
}

__global__ void zero_out_kernel(float* __restrict__ out) {
    if (threadIdx.x == 0) out[0] = 0.0f;
}

// ---------------------------------------------------------------------------
// Kernel B: block = (angle, quadrant). Stage the quadrant (+apron) into LDS,
// then thread d marches its ray's exact sample sub-range inside the quadrant
// box (half-open clip -> each sample owned by exactly one quadrant).
// Bilinear fetch = 2x ds_read2_b32 (aligned word pair per row) + v_alignbit
// funnel shift extracting the unaligned byte pair + 2 HW fp8 unpacks.
// Per-thread partial -> S plane (plain store, no atomics).
// ---------------------------------------------------------------------------
__global__ __launch_bounds__(448) void proj_lds(const unsigned int* __restrict__ G,
                                                float* __restrict__ S,
                                                float theta_step, float gmax,
                                                float gstep, float t0,
                                                float dtstep) {
    __shared__ unsigned int L[LROWS * LWPR];       // 53808 B -> 3 blocks/CU

    const int blk = blockIdx.x;          // 0..1279
    const int a  = blk >> 2;
    const int q  = blk & 3;
    const int qi = q >> 1, qj = q & 1;
    const int r0 = qi ? 222 : -2;        // first staged pixel row
    const int c0 = qj ? 220 : -4;        // first staged pixel col (word-aligned)
    const int nrows = qi ? 198 : 228;    // +1 slop margin row vs box top

    // --- cooperative stage: nrows x 59 dwords, ALL words defined -----------
    {
        const int gbase = ((r0 + 8) * GSTRIDE + (c0 + 8)) >> 2;  // word index
        const int total = nrows * LWPR;
        for (int i = threadIdx.x; i < total; i += 448) {
            int rr = i / LWPR;
            int cc = i - rr * LWPR;
            L[rr * LWPR + cc] = G[gbase + rr * 116 + cc];
        }
    }
    __syncthreads();

    const int d = threadIdx.x;
    if (d < N_DET) {
        const float theta = (float)a * theta_step;
        const float gamma = fmaf((float)d, gstep, -gmax);
        float s1, c1, s2, c2;
        sincosf(theta, &s1, &c1);
        sincosf(theta + gamma, &s2, &c2);
        const float sx = fmaf(1075.0f, c1, 207.5f);
        const float sy = fmaf(1075.0f, s1, 207.5f);

        // col(k) = C0 - k*dc ; row(k) = R0 - k*dr   (k = 0..415)
        const float C0 = fmaf(-t0, c2, sx), dc = dtstep * c2;
        const float R0 = fmaf(-t0, s2, sy), dr = dtstep * s2;

        // quadrant box, half-open: col in [cl,ch), row in [rl,rh)
        const float cl = qj ? 224.0f : -2.0f, ch = qj ? 418.0f : 224.0f;
        const float rl = qi ? 224.0f : -2.0f, rh = qi ? 418.0f : 224.0f;

        int klo = 0, khi = N_SAMP - 1;
        auto clip1 = [&](float X0, float dX, float lo, float hi) {
            if (fabsf(dX) < 1e-8f) {
                if (!(X0 >= lo && X0 < hi)) { klo = 1; khi = 0; }
            } else {
                float x1 = (X0 - hi) / dX;        // strict side
                float x2 = (X0 - lo) / dX;        // inclusive side
                x1 = fminf(fmaxf(x1, -1e6f), 1e6f);
                x2 = fminf(fmaxf(x2, -1e6f), 1e6f);
                int lo_k, hi_k;
                if (dX > 0.0f) { lo_k = (int)floorf(x1) + 1; hi_k = (int)floorf(x2); }
                else           { lo_k = (int)ceilf(x2);      hi_k = (int)ceilf(x1) - 1; }
                klo = max(klo, lo_k);
                khi = min(khi, hi_k);
            }
        };
        clip1(C0, dc, cl, ch);
        clip1(R0, dr, rl, rh);

        float acc = 0.0f;
        if (klo <= khi) {
            // LDS-relative coords (always >= 0 inside the box -> trunc==floor)
            float colR = fmaf(-(float)klo, dc, C0) - (float)c0;
            float rowR = fmaf(-(float)klo, dr, R0) - (float)r0;
            #pragma unroll 4
            for (int k = klo; k <= khi; ++k) {
                const int ci = (int)colR;
                const int ri = (int)rowR;
                const float wc = colR - (float)ci;
                const float wr = rowR - (float)ri;
                const int bb = ri * LSTRIDE + ci;      // byte index
                const int wi = bb >> 2;
                const unsigned int sh = (unsigned)(bb & 3) * 8u;
                const unsigned int w0 = L[wi];
                const unsigned int w1 = L[wi + 1];
                const unsigned int w2 = L[wi + LWPR];
                const unsigned int w3 = L[wi + LWPR + 1];
                // funnel shift -> bytes (bb, bb+1) in low 16 bits
                const unsigned int top16 = __builtin_amdgcn_alignbit(w1, w0, sh);
                const unsigned int bot16 = __builtin_amdgcn_alignbit(w3, w2, sh);
                const vfloat2 X = __builtin_amdgcn_cvt_pk_f32_fp8(top16, false); // v00,v01
                const vfloat2 Y = __builtin_amdgcn_cvt_pk_f32_fp8(bot16, false); // v10,v11
                const float top = fmaf(wc, X[1] - X[0], X[0]);
                const float bot = fmaf(wc, Y[1] - Y[0], Y[0]);
                acc = fmaf(wr, bot - top, acc + top);
                colR -= dc;
                rowR -= dr;
            }
        }
        S[q * SPLANE + a * N_DET + d] = acc;
    }
}

// ---------------------------------------------------------------------------
// Kernel C: combine the 4 quadrant partials per ray, square, reduce, scale.
// ---------------------------------------------------------------------------
__global__ __launch_bounds__(256) void reduce_kernel(const float* __restrict__ S,
                                                     float* __restrict__ out,
                                                     float coef) {
    const int i = blockIdx.x * 256 + threadIdx.x;
    float v = 0.0f;
    if (i < SPLANE)
        v = (S[i] + S[SPLANE + i]) + (S[2 * SPLANE + i] + S[3 * SPLANE + i]);
    float sq = v * v;
    #pragma unroll
    for (int m = 32; m > 0; m >>= 1) sq += __shfl_down(sq, m, 64);
    __shared__ float w[4];
    const int lane = threadIdx.x & 63;
    if (lane == 0) w[threadIdx.x >> 6] = sq;
    __syncthreads();
    if (threadIdx.x == 0)
        atomicAdd(out, (w[0] + w[1] + w[2] + w[3]) * coef);
}

// ---------------------------------------------------------------------------
// Fallback (ws too small): fused one-thread-per-ray fp32 gather version.
// ---------------------------------------------------------------------------
__global__ __launch_bounds__(256) void proj_fused(const float* __restrict__ imgA,
                                                  const float* __restrict__ imgB,
                                                  float* __restrict__ out,
                                                  float theta_step, float gmax,
                                                  float gstep, float t0,
                                                  float dtstep, float coef) {
    const int idx = blockIdx.x * 256 + threadIdx.x;
    const int a  = idx / N_DET;
    const int dd = idx - a * N_DET;
    const float theta = (float)a * theta_step;
    const float gamma = fmaf((float)dd, gstep, -gmax);
    float s1, c1, s2, c2;
    sincosf(theta, &s1, &c1);
    sincosf(theta + gamma, &s2, &c2);
    const float sx = 1075.0f * c1 + 207.5f;
    const float sy = 1075.0f * s1 + 207.5f;
    float acc = 0.0f;
    #pragma unroll 4
    for (int s = 0; s < N_SAMP; ++s) {
        const float t   = fmaf((float)s, dtstep, t0);
        const float col = fmaf(-t, c2, sx);
        const float row = fmaf(-t, s2, sy);
        const float c0 = floorf(col);
        const float r0 = floorf(row);
        const float wc = col - c0;
        const float wr = row - r0;
        const int ci = (int)c0;
        const int ri = (int)r0;
        auto Gv = [&](int r, int c) -> float {
            if ((unsigned)r < (unsigned)IMG && (unsigned)c < (unsigned)IMG)
                return imgA[r * IMG + c] - imgB[r * IMG + c];
            return 0.0f;
        };
        const float v00 = Gv(ri, ci);
        const float v01 = Gv(ri, ci + 1);
        const float v10 = Gv(ri + 1, ci);
        const float v11 = Gv(ri + 1, ci + 1);
        const float top = fmaf(wc, v01 - v00, v00);
        const float bot = fmaf(wc, v11 - v10, v10);
        acc += fmaf(wr, bot - top, top);
    }
    float sq = acc * acc;
    #pragma unroll
    for (int o = 32; o > 0; o >>= 1) sq += __shfl_down(sq, o, 64);
    __shared__ float wsum[4];
    const int lane = threadIdx.x & 63;
    if (lane == 0) wsum[threadIdx.x >> 6] = sq;
    __syncthreads();
    if (threadIdx.x == 0)
        atomicAdd(out, (wsum[0] + wsum[1] + wsum[2] + wsum[3]) * coef);
}

extern "C" void kernel_launch(void* const* d_in, const int* in_sizes, int n_in,
                              void* d_out, int out_size, void* d_ws, size_t ws_size,
                              hipStream_t stream) {
    const float* in = (const float*)d_in[0];
    const float* tg = (const float*)d_in[1];
    float* out = (float*)d_out;

    const double half_diag = (IMG / 2.0) * sqrt(2.0);
    const double ray_len   = IMG * sqrt(2.0);
    const float  gmax      = (float)asin(half_diag / 1075.0);
    const float  gstep     = (float)(2.0 * (double)gmax / (N_DET - 1));
    const float  t0        = (float)(1075.0 - ray_len / 2.0);
    const float  dtstep    = (float)(ray_len / (N_SAMP - 1));
    const float  theta_step = (float)(2.0 * M_PI / N_ANG);
    const double dt        = ray_len / (N_SAMP - 1);
    const double SCALE     = 512.0 / 416.0 * 0.03;
    const float  coef      = (float)(dt * dt * SCALE / ((double)N_ANG * N_DET));

    if (ws_size >= WSNEED) {
        unsigned int* G = (unsigned int*)d_ws;
        float* S = (float*)((char*)d_ws + GBYTES);
        pack_kernel<<<(GWORDS + 255) / 256, 256, 0, stream>>>(in, tg, G, out);
        proj_lds<<<N_ANG * 4, 448, 0, stream>>>(G, S, theta_step, gmax, gstep,
                                                t0, dtstep);
        reduce_kernel<<<SPLANE / 256, 256, 0, stream>>>(S, out, coef);
    } else {
        zero_out_kernel<<<1, 64, 0, stream>>>(out);
        proj_fused<<<(N_ANG * N_DET) / 256, 256, 0, stream>>>(
            in, tg, out, theta_step, gmax, gstep, t0, dtstep, coef);
    }
}